// Round 10
// baseline (1900.122 us; speedup 1.0000x reference)
//
#include <hip/hip_runtime.h>
#include <hip/hip_bf16.h>
#include <math.h>
#include <stdint.h>

// HolomorphicEqProp: B=4096, D_IN=H=1024, D_OUT=256, steps=30.
// Round-10: barrier-free streaming design. Each block owns 16 batch rows x
// full H => NO cross-block communication (R6-validated decomposition). h
// ping-pongs in LDS (chunked layout); xproj in registers; Wr b-frags read
// DIRECTLY from global (L2-resident, no LDS staging, no per-step barriers
// except one __syncthreads). xproj GEMM and output GEMM fused in-kernel.
// R8/R9 post-mortem: any cross-block h exchange pays agent-scope wbl2+inv
// (~25us/step) — structurally avoided here.

#define EPSF 1e-12f

typedef short bf16x8 __attribute__((ext_vector_type(8)));
typedef float f32x4 __attribute__((ext_vector_type(4)));

struct Mods { float m[32]; };

__device__ __forceinline__ unsigned short f2bf(float f) {
  union { float f; unsigned u; } v; v.f = f;
  unsigned r = v.u + 0x7FFFu + ((v.u >> 16) & 1u);  // RNE
  return (unsigned short)(r >> 16);
}

__device__ __forceinline__ float block_reduce_sum(float x) {
#pragma unroll
  for (int o = 32; o > 0; o >>= 1) x += __shfl_down(x, o, 64);
  __shared__ float sm[8];
  int lane = threadIdx.x & 63, w = threadIdx.x >> 6;
  if (lane == 0) sm[w] = x;
  __syncthreads();
  float t = 0.f;
  if (threadIdx.x == 0) {
    int nw = (int)(blockDim.x >> 6);
    for (int i = 0; i < nw; ++i) t += sm[i];
  }
  return t;
}

// ---------------- fused spectral-norm setup (fp32, exact; validated) -------

__global__ void spec_col3(const float* __restrict__ Wi, const float* __restrict__ Wr,
                          const float* __restrict__ Wo, const float* __restrict__ ui,
                          const float* __restrict__ ur, const float* __restrict__ uo,
                          float* __restrict__ v) {
  int z = blockIdx.z;
  const float* W = (z == 0) ? Wi : (z == 1) ? Wr : Wo;
  const float* u = (z == 0) ? ui : (z == 1) ? ur : uo;
  int M = (z == 2) ? 256 : 1024;
  int i0 = blockIdx.y * 64;
  if (i0 >= M) return;
  int j = blockIdx.x * blockDim.x + threadIdx.x;
  float acc = 0.f;
  for (int i = i0; i < i0 + 64; ++i)
    acc += W[(size_t)i * 1024 + j] * u[i];
  atomicAdd(&v[z * 1024 + j], acc);
}

__global__ void norm3(const float* __restrict__ v, float* __restrict__ S) {
  int z = blockIdx.x;
  float acc = 0.f;
  for (int i = threadIdx.x; i < 1024; i += blockDim.x) {
    float x = v[z * 1024 + i];
    acc += x * x;
  }
  float t = block_reduce_sum(acc);
  if (threadIdx.x == 0) S[z] = t;
}

__global__ void rowsq3(const float* __restrict__ Wi, const float* __restrict__ Wr,
                       const float* __restrict__ Wo, const float* __restrict__ v,
                       float* __restrict__ S) {
  int bid = blockIdx.x;
  int z = (bid < 1024) ? 0 : (bid < 2048) ? 1 : 2;
  int row = bid - ((z == 0) ? 0 : (z == 1) ? 1024 : 2048);
  const float* W = (z == 0) ? Wi : (z == 1) ? Wr : Wo;
  const float* vv = v + z * 1024;
  float acc = 0.f;
  for (int j = threadIdx.x; j < 1024; j += blockDim.x)
    acc += W[(size_t)row * 1024 + j] * vv[j];
  float r = block_reduce_sum(acc);
  if (threadIdx.x == 0) atomicAdd(&S[3 + z], r * r);
}

__global__ void spec_finalize(float* S) {
  int m = threadIdx.x;
  if (m < 3) {
    float nv = sqrtf(S[m]);
    float inv = 1.f / (nv + EPSF);
    float u2sq = S[3 + m] * inv * inv;
    float nu = sqrtf(u2sq);
    float sigma = u2sq / (nu + EPSF);
    S[6 + m] = 1.f / sigma;
  }
}

__device__ __forceinline__ ushort4 cvt4e(float4 w, float s) {
  ushort4 r;
  r.x = f2bf(w.x * s); r.y = f2bf(w.y * s); r.z = f2bf(w.z * s); r.w = f2bf(w.w * s);
  return r;
}

__global__ void cvt_all(const float4* __restrict__ Wi, const float4* __restrict__ Wr,
                        const float4* __restrict__ Wo, const float4* __restrict__ x,
                        const float* __restrict__ S,
                        ushort4* __restrict__ oWi, ushort4* __restrict__ oWr,
                        ushort4* __restrict__ oWo, ushort4* __restrict__ ox) {
  float s6 = S[6], s7 = S[7], s8 = S[8];
  int stride = gridDim.x * blockDim.x;
  int t0 = blockIdx.x * blockDim.x + threadIdx.x;
  for (int i = t0; i < 262144; i += stride) oWi[i] = cvt4e(Wi[i], s6);
  for (int i = t0; i < 262144; i += stride) oWr[i] = cvt4e(Wr[i], s7);
  for (int i = t0; i < 65536; i += stride) oWo[i] = cvt4e(Wo[i], s8);
  for (int i = t0; i < 1048576; i += stride) ox[i] = cvt4e(x[i], 1.0f);
}

// ---------------- streaming RNN kernel ----------------
//
// 256 blocks x 512 threads (8 waves). Block b: batch rows [b*16, +16).
// Wave w: output cols [w*128, +128) (8 n-frags), or [w*32, +32) for D_OUT.
// h tile in LDS, CHUNKED layout: elem(m,k) at (k>>5)*512 + m*32 + (k&31)
// (matches the validated gemm fragment math; a-reads 2-way-aliased = free).
// B-operand (Wi/Wr/Wo) read directly from global: per frag, lane reads
// W[(c0 + nf*16 + lrow)*1024 + kc*32 + quad*8], 16B — L2-resident rows.

template <int NF>
__device__ __forceinline__ void sweep_g(
    const unsigned short* __restrict__ Bg,  // W + c0*1024 (wave's col base)
    const unsigned short* hk,               // LDS base of current h buffer
    int lrow, int quad, f32x4* acc) {
  const unsigned short* bl = Bg + (size_t)lrow * 1024 + quad * 8;
  bf16x8 bc[NF], bn[NF];
#pragma unroll
  for (int nf = 0; nf < NF; ++nf)
    bc[nf] = *(const bf16x8*)(bl + nf * 16384);
#pragma unroll 1
  for (int kb = 0; kb < 32; kb += 2) {
    // even chunk kb: use bc, prefetch kb+1 -> bn
#pragma unroll
    for (int nf = 0; nf < NF; ++nf)
      bn[nf] = *(const bf16x8*)(bl + nf * 16384 + (kb + 1) * 32);
    {
      bf16x8 a = *(const bf16x8*)&hk[kb * 512 + lrow * 32 + quad * 8];
#pragma unroll
      for (int nf = 0; nf < NF; ++nf)
        acc[nf] = __builtin_amdgcn_mfma_f32_16x16x32_bf16(a, bc[nf], acc[nf], 0, 0, 0);
    }
    // odd chunk kb+1: use bn, prefetch kb+2 -> bc (wraps at end; dead loads)
    {
      const int k2 = (kb + 2) & 31;
#pragma unroll
      for (int nf = 0; nf < NF; ++nf)
        bc[nf] = *(const bf16x8*)(bl + nf * 16384 + k2 * 32);
      bf16x8 a = *(const bf16x8*)&hk[(kb + 1) * 512 + lrow * 32 + quad * 8];
#pragma unroll
      for (int nf = 0; nf < NF; ++nf)
        acc[nf] = __builtin_amdgcn_mfma_f32_16x16x32_bf16(a, bn[nf], acc[nf], 0, 0, 0);
    }
  }
}

__global__ __launch_bounds__(512, 1) void rnn_stream(
    const unsigned short* __restrict__ x_bf,  // [4096][1024] bf16
    const unsigned short* __restrict__ Wi,    // [1024][1024] bf16 (scaled)
    const unsigned short* __restrict__ Wr,    // [1024][1024] bf16 (scaled)
    const unsigned short* __restrict__ Wo,    // [256][1024] bf16 (scaled)
    const float* __restrict__ b_in,
    const float* __restrict__ b_rec,
    const float* __restrict__ b_out,
    float* __restrict__ out,                  // [4096][256] f32
    Mods mods) {
  __shared__ __align__(16) unsigned short hk[2 * 16384];  // 64 KiB ping-pong

  const int tid = threadIdx.x;
  const int w = tid >> 6, lane = tid & 63;
  const int lrow = lane & 15, quad = lane >> 4;
  const int m0 = (int)blockIdx.x * 16;
  const int c0 = w * 128;

  // biases for this wave's 8 col-frags
  float bin[8], brec[8];
#pragma unroll
  for (int nf = 0; nf < 8; ++nf) {
    bin[nf] = b_in[c0 + nf * 16 + lrow];
    brec[nf] = b_rec[c0 + nf * 16 + lrow];
  }

  // ---- stage x tile -> hk[0] (chunked layout) ----
  {
    int row = tid & 15, ch = tid >> 4;  // ch in [0,32)
    const unsigned short* src = x_bf + (size_t)(m0 + row) * 1024 + ch * 32;
    unsigned short* dst = hk + ch * 512 + row * 32;
#pragma unroll
    for (int j = 0; j < 4; ++j)
      *(bf16x8*)(dst + j * 8) = *(const bf16x8*)(src + j * 8);
  }
  __syncthreads();

  // ---- xproj = x @ Wi^T + b_in (registers, C-layout) ----
  float xpr[8][4];
  {
    f32x4 xacc[8] = {};
    sweep_g<8>(Wi + (size_t)c0 * 1024, hk, lrow, quad, xacc);
#pragma unroll
    for (int nf = 0; nf < 8; ++nf)
#pragma unroll
      for (int r = 0; r < 4; ++r)
        xpr[nf][r] = xacc[nf][r] + bin[nf];
  }
  __syncthreads();  // all hk[0] (x) reads done

  // ---- t=0: h0 = tanh(xproj + b_rec), mod(0)=1 -> hk[1] ----
#pragma unroll
  for (int nf = 0; nf < 8; ++nf) {
    int n = c0 + nf * 16 + lrow;
    unsigned short* dst = hk + 16384 + (n >> 5) * 512 + (n & 31);
#pragma unroll
    for (int r = 0; r < 4; ++r)
      dst[(quad * 4 + r) * 32] = f2bf(tanhf(xpr[nf][r] + brec[nf]));
  }
  __syncthreads();

  // ---- steps t = 1..29: read hk[cur], write hk[nxt] ----
  unsigned cur = 16384, nxt = 0;
#pragma unroll 1
  for (int t = 1; t < 30; ++t) {
    const float mod = mods.m[t];
    f32x4 acc[8] = {};
    sweep_g<8>(Wr + (size_t)c0 * 1024, hk + cur, lrow, quad, acc);
#pragma unroll
    for (int nf = 0; nf < 8; ++nf) {
      int n = c0 + nf * 16 + lrow;
      unsigned short* dst = hk + nxt + (n >> 5) * 512 + (n & 31);
#pragma unroll
      for (int r = 0; r < 4; ++r)
        dst[(quad * 4 + r) * 32] =
            f2bf(tanhf(xpr[nf][r] + (acc[nf][r] + brec[nf]) * mod));
    }
    __syncthreads();  // nxt published; cur reads finished
    unsigned tmp = cur; cur = nxt; nxt = tmp;
  }

  // ---- out = h29 @ Wo^T + b_out (wave w: cols [w*32,+32)) ----
  {
    f32x4 oacc[2] = {};
    sweep_g<2>(Wo + (size_t)(w * 32) * 1024, hk + cur, lrow, quad, oacc);
#pragma unroll
    for (int nf = 0; nf < 2; ++nf) {
      int col = w * 32 + nf * 16 + lrow;
      float bv = b_out[col];
#pragma unroll
      for (int r = 0; r < 4; ++r)
        out[(size_t)(m0 + quad * 4 + r) * 256 + col] = oacc[nf][r] + bv;
    }
  }
}

extern "C" void kernel_launch(void* const* d_in, const int* in_sizes, int n_in,
                              void* d_out, int out_size, void* d_ws, size_t ws_size,
                              hipStream_t stream) {
  const float* x     = (const float*)d_in[0];
  const float* W_in  = (const float*)d_in[1];
  const float* b_in  = (const float*)d_in[2];
  const float* W_rec = (const float*)d_in[3];
  const float* b_rec = (const float*)d_in[4];
  const float* W_out = (const float*)d_in[5];
  const float* b_out = (const float*)d_in[6];
  const float* u_in  = (const float*)d_in[7];
  const float* u_rec = (const float*)d_in[8];
  const float* u_out = (const float*)d_in[9];

  const int B = 4096, H = 1024, DOUT = 256;

  char* w = (char*)d_ws;
  float* S = (float*)w;                          // 256 floats
  float* v = S + 256;                            // 3 x 1024 floats
  unsigned short* Wi_bf = (unsigned short*)(w + (1 << 14));
  unsigned short* Wr_bf = Wi_bf + (size_t)H * H;
  unsigned short* Wo_bf = Wr_bf + (size_t)H * H;
  unsigned short* x_bf  = Wo_bf + (size_t)DOUT * H;

  hipMemsetAsync(w, 0, 1 << 14, stream);  // zero S, v

  dim3 t256(256);
  spec_col3<<<dim3(4, 16, 3), t256, 0, stream>>>(W_in, W_rec, W_out, u_in, u_rec, u_out, v);
  norm3<<<3, t256, 0, stream>>>(v, S);
  rowsq3<<<2304, t256, 0, stream>>>(W_in, W_rec, W_out, v, S);
  spec_finalize<<<1, 64, 0, stream>>>(S);
  cvt_all<<<1024, t256, 0, stream>>>((const float4*)W_in, (const float4*)W_rec,
                                     (const float4*)W_out, (const float4*)x, S,
                                     (ushort4*)Wi_bf, (ushort4*)Wr_bf,
                                     (ushort4*)Wo_bf, (ushort4*)x_bf);

  Mods mods;
  for (int t = 0; t < 32; ++t) mods.m[t] = (float)(1.0 + 0.1 * sin(0.3 * (double)t));

  rnn_stream<<<256, 512, 0, stream>>>(x_bf, Wi_bf, Wr_bf, Wo_bf,
                                      b_in, b_rec, b_out, (float*)d_out, mods);
}

// Round 12
// 1193.730 us; speedup vs baseline: 1.5918x; 1.5918x over previous
//
#include <hip/hip_runtime.h>
#include <hip/hip_bf16.h>
#include <math.h>
#include <stdint.h>

// HolomorphicEqProp: B=4096, D_IN=H=1024, D_OUT=256, steps=30.
// Round-12: R11 (barrier-free streaming + frag-major-packed W) with the
// pack-density bug fixed. R11 spaced 512-element b-frags 1024 elements apart:
// Wo's packed image overran its buffer into x_bf (absmax 112) and Wi/Wr
// wasted 2x L2 footprint. Dense spacing: frag block (ng,kc) at
// (ng*32+kc)*512; elem(n,k) offset ((k>>3)&3)*128 + (n&15)*8 + (k&7).
// Every b-frag load = one contiguous 1 KB wave burst (fixes R10's
// transaction-rate wall). h in LDS ping-pong; no cross-block traffic
// (R8/R9: agent-scope exchange costs ~25us/step in wbl2+inv).

#define EPSF 1e-12f

typedef short bf16x8 __attribute__((ext_vector_type(8)));
typedef float f32x4 __attribute__((ext_vector_type(4)));

struct Mods { float m[32]; };

__device__ __forceinline__ unsigned short f2bf(float f) {
  union { float f; unsigned u; } v; v.f = f;
  unsigned r = v.u + 0x7FFFu + ((v.u >> 16) & 1u);  // RNE
  return (unsigned short)(r >> 16);
}

__device__ __forceinline__ float block_reduce_sum(float x) {
#pragma unroll
  for (int o = 32; o > 0; o >>= 1) x += __shfl_down(x, o, 64);
  __shared__ float sm[8];
  int lane = threadIdx.x & 63, w = threadIdx.x >> 6;
  if (lane == 0) sm[w] = x;
  __syncthreads();
  float t = 0.f;
  if (threadIdx.x == 0) {
    int nw = (int)(blockDim.x >> 6);
    for (int i = 0; i < nw; ++i) t += sm[i];
  }
  return t;
}

// ---------------- fused spectral-norm setup (fp32, exact; validated) -------

__global__ void spec_col3(const float* __restrict__ Wi, const float* __restrict__ Wr,
                          const float* __restrict__ Wo, const float* __restrict__ ui,
                          const float* __restrict__ ur, const float* __restrict__ uo,
                          float* __restrict__ v) {
  int z = blockIdx.z;
  const float* W = (z == 0) ? Wi : (z == 1) ? Wr : Wo;
  const float* u = (z == 0) ? ui : (z == 1) ? ur : uo;
  int M = (z == 2) ? 256 : 1024;
  int i0 = blockIdx.y * 64;
  if (i0 >= M) return;
  int j = blockIdx.x * blockDim.x + threadIdx.x;
  float acc = 0.f;
  for (int i = i0; i < i0 + 64; ++i)
    acc += W[(size_t)i * 1024 + j] * u[i];
  atomicAdd(&v[z * 1024 + j], acc);
}

__global__ void norm3(const float* __restrict__ v, float* __restrict__ S) {
  int z = blockIdx.x;
  float acc = 0.f;
  for (int i = threadIdx.x; i < 1024; i += blockDim.x) {
    float x = v[z * 1024 + i];
    acc += x * x;
  }
  float t = block_reduce_sum(acc);
  if (threadIdx.x == 0) S[z] = t;
}

__global__ void rowsq3(const float* __restrict__ Wi, const float* __restrict__ Wr,
                       const float* __restrict__ Wo, const float* __restrict__ v,
                       float* __restrict__ S) {
  int bid = blockIdx.x;
  int z = (bid < 1024) ? 0 : (bid < 2048) ? 1 : 2;
  int row = bid - ((z == 0) ? 0 : (z == 1) ? 1024 : 2048);
  const float* W = (z == 0) ? Wi : (z == 1) ? Wr : Wo;
  const float* vv = v + z * 1024;
  float acc = 0.f;
  for (int j = threadIdx.x; j < 1024; j += blockDim.x)
    acc += W[(size_t)row * 1024 + j] * vv[j];
  float r = block_reduce_sum(acc);
  if (threadIdx.x == 0) atomicAdd(&S[3 + z], r * r);
}

__global__ void spec_finalize(float* S) {
  int m = threadIdx.x;
  if (m < 3) {
    float nv = sqrtf(S[m]);
    float inv = 1.f / (nv + EPSF);
    float u2sq = S[3 + m] * inv * inv;
    float nu = sqrtf(u2sq);
    float sigma = u2sq / (nu + EPSF);
    S[6 + m] = 1.f / sigma;
  }
}

// convert + pack one 8-k group of row n into DENSE frag-major layout:
// frag block (n>>4, k0>>5) at block*512; within: quad_k*128 + (n&15)*8 + (k&7)
__device__ __forceinline__ void pack8(const float4* __restrict__ W, float s,
                                      unsigned short* __restrict__ o, int n, int k0) {
  float4 w0 = W[(n * 1024 + k0) >> 2];
  float4 w1 = W[(n * 1024 + k0 + 4) >> 2];
  bf16x8 r;
  r[0] = (short)f2bf(w0.x * s); r[1] = (short)f2bf(w0.y * s);
  r[2] = (short)f2bf(w0.z * s); r[3] = (short)f2bf(w0.w * s);
  r[4] = (short)f2bf(w1.x * s); r[5] = (short)f2bf(w1.y * s);
  r[6] = (short)f2bf(w1.z * s); r[7] = (short)f2bf(w1.w * s);
  int off = ((n >> 4) * 32 + (k0 >> 5)) * 512 + ((k0 >> 3) & 3) * 128 + (n & 15) * 8;
  *(bf16x8*)(o + off) = r;
}

__device__ __forceinline__ ushort4 cvt4e(float4 w, float s) {
  ushort4 r;
  r.x = f2bf(w.x * s); r.y = f2bf(w.y * s); r.z = f2bf(w.z * s); r.w = f2bf(w.w * s);
  return r;
}

// convert + pack Wi/Wr/Wo (frag-major dense) and convert x (row-major)
__global__ void cvt_pack_all(const float4* __restrict__ Wi, const float4* __restrict__ Wr,
                             const float4* __restrict__ Wo, const float4* __restrict__ x,
                             const float* __restrict__ S,
                             unsigned short* __restrict__ oWi, unsigned short* __restrict__ oWr,
                             unsigned short* __restrict__ oWo, ushort4* __restrict__ ox) {
  float s6 = S[6], s7 = S[7], s8 = S[8];
  int stride = gridDim.x * blockDim.x;
  int t0 = blockIdx.x * blockDim.x + threadIdx.x;
  for (int i = t0; i < 131072; i += stride)
    pack8(Wi, s6, oWi, i >> 7, (i & 127) << 3);
  for (int i = t0; i < 131072; i += stride)
    pack8(Wr, s7, oWr, i >> 7, (i & 127) << 3);
  for (int i = t0; i < 32768; i += stride)
    pack8(Wo, s8, oWo, i >> 7, (i & 127) << 3);
  for (int i = t0; i < 1048576; i += stride) ox[i] = cvt4e(x[i], 1.0f);
}

// ---------------- streaming RNN kernel ----------------
//
// 256 blocks x 512 threads (8 waves). Block b: batch rows [b*16, +16).
// Wave w: output cols [w*128, +128) (8 n-frag-groups), or [w*32,+32) for out.
// h in LDS ping-pong, chunked layout: elem(m,k) at (k>>5)*512 + m*32 + (k&31).
// Packed W: frag-group ng spans 32 frags x 512 = 16384 elems; frag kc at
// +kc*512; lane reads frag + lane*8 (one 1 KB coalesced burst per load).

template <int NF>
__device__ __forceinline__ void sweep_p(
    const unsigned short* __restrict__ Bp,  // packed W + ng0*16384
    const unsigned short* hk,               // LDS base of current h buffer
    int lane, int lrow, int quad, f32x4* acc) {
#pragma unroll
  for (int nf = 0; nf < NF; ++nf) {
    const unsigned short* fb = Bp + nf * 16384 + lane * 8;
    bf16x8 pb[8];
#pragma unroll
    for (int i = 0; i < 8; ++i) pb[i] = *(const bf16x8*)(fb + i * 512);
#pragma unroll 1
    for (int kb = 0; kb < 32; kb += 8) {
#define PHASE(P)                                                               \
      {                                                                        \
        const int kc = kb + P;                                                 \
        bf16x8 a = *(const bf16x8*)&hk[kc * 512 + lrow * 32 + quad * 8];       \
        acc[nf] = __builtin_amdgcn_mfma_f32_16x16x32_bf16(a, pb[P], acc[nf], 0, 0, 0); \
        pb[P] = *(const bf16x8*)(fb + ((kc + 8) & 31) * 512);                  \
      }
      PHASE(0) PHASE(1) PHASE(2) PHASE(3) PHASE(4) PHASE(5) PHASE(6) PHASE(7)
#undef PHASE
    }
  }
}

__global__ __launch_bounds__(512, 1) void rnn_stream(
    const unsigned short* __restrict__ x_bf,  // [4096][1024] bf16 row-major
    const unsigned short* __restrict__ Wi,    // packed frag-major (1M elems)
    const unsigned short* __restrict__ Wr,    // packed frag-major (1M elems)
    const unsigned short* __restrict__ Wo,    // packed frag-major (256K elems)
    const float* __restrict__ b_in,
    const float* __restrict__ b_rec,
    const float* __restrict__ b_out,
    float* __restrict__ out,                  // [4096][256] f32
    Mods mods) {
  __shared__ __align__(16) unsigned short hk[2 * 16384];  // 64 KiB ping-pong

  const int tid = threadIdx.x;
  const int w = tid >> 6, lane = tid & 63;
  const int lrow = lane & 15, quad = lane >> 4;
  const int m0 = (int)blockIdx.x * 16;
  const int c0 = w * 128;

  float bin[8], brec[8];
#pragma unroll
  for (int nf = 0; nf < 8; ++nf) {
    bin[nf] = b_in[c0 + nf * 16 + lrow];
    brec[nf] = b_rec[c0 + nf * 16 + lrow];
  }

  // ---- stage x tile -> hk[0] (chunked layout) ----
  {
    int row = tid & 15, ch = tid >> 4;  // ch in [0,32)
    const unsigned short* src = x_bf + (size_t)(m0 + row) * 1024 + ch * 32;
    unsigned short* dst = hk + ch * 512 + row * 32;
#pragma unroll
    for (int j = 0; j < 4; ++j)
      *(bf16x8*)(dst + j * 8) = *(const bf16x8*)(src + j * 8);
  }
  __syncthreads();

  // ---- xproj = x @ Wi^T + b_in (registers, C-layout) ----
  float xpr[8][4];
  {
    f32x4 xacc[8] = {};
    sweep_p<8>(Wi + (size_t)w * 131072, hk, lane, lrow, quad, xacc);
#pragma unroll
    for (int nf = 0; nf < 8; ++nf)
#pragma unroll
      for (int r = 0; r < 4; ++r)
        xpr[nf][r] = xacc[nf][r] + bin[nf];
  }
  __syncthreads();  // all hk[0] (x) reads done

  // ---- t=0: h0 = tanh(xproj + b_rec), mod(0)=1 -> hk[1] ----
#pragma unroll
  for (int nf = 0; nf < 8; ++nf) {
    int n = c0 + nf * 16 + lrow;
    unsigned short* dst = hk + 16384 + (n >> 5) * 512 + (n & 31);
#pragma unroll
    for (int r = 0; r < 4; ++r)
      dst[(quad * 4 + r) * 32] = f2bf(tanhf(xpr[nf][r] + brec[nf]));
  }
  __syncthreads();

  // ---- steps t = 1..29: read hk[cur], write hk[nxt] ----
  unsigned cur = 16384, nxt = 0;
#pragma unroll 1
  for (int t = 1; t < 30; ++t) {
    const float mod = mods.m[t];
    f32x4 acc[8] = {};
    sweep_p<8>(Wr + (size_t)w * 131072, hk + cur, lane, lrow, quad, acc);
#pragma unroll
    for (int nf = 0; nf < 8; ++nf) {
      int n = c0 + nf * 16 + lrow;
      unsigned short* dst = hk + nxt + (n >> 5) * 512 + (n & 31);
#pragma unroll
      for (int r = 0; r < 4; ++r)
        dst[(quad * 4 + r) * 32] =
            f2bf(tanhf(xpr[nf][r] + (acc[nf][r] + brec[nf]) * mod));
    }
    __syncthreads();  // nxt published; cur reads finished
    unsigned tmp = cur; cur = nxt; nxt = tmp;
  }

  // ---- out = h29 @ Wo^T + b_out (wave w: cols [w*32,+32)) ----
  {
    f32x4 oacc[2] = {};
    sweep_p<2>(Wo + (size_t)w * 32768, hk + cur, lane, lrow, quad, oacc);
#pragma unroll
    for (int nf = 0; nf < 2; ++nf) {
      int col = w * 32 + nf * 16 + lrow;
      float bv = b_out[col];
#pragma unroll
      for (int r = 0; r < 4; ++r)
        out[(size_t)(m0 + quad * 4 + r) * 256 + col] = oacc[nf][r] + bv;
    }
  }
}

extern "C" void kernel_launch(void* const* d_in, const int* in_sizes, int n_in,
                              void* d_out, int out_size, void* d_ws, size_t ws_size,
                              hipStream_t stream) {
  const float* x     = (const float*)d_in[0];
  const float* W_in  = (const float*)d_in[1];
  const float* b_in  = (const float*)d_in[2];
  const float* W_rec = (const float*)d_in[3];
  const float* b_rec = (const float*)d_in[4];
  const float* W_out = (const float*)d_in[5];
  const float* b_out = (const float*)d_in[6];
  const float* u_in  = (const float*)d_in[7];
  const float* u_rec = (const float*)d_in[8];
  const float* u_out = (const float*)d_in[9];

  const int B = 4096, H = 1024, DOUT = 256;

  char* w = (char*)d_ws;
  float* S = (float*)w;                          // 256 floats
  float* v = S + 256;                            // 3 x 1024 floats
  unsigned short* Wi_bf = (unsigned short*)(w + (1 << 14));
  unsigned short* Wr_bf = Wi_bf + (size_t)H * H;
  unsigned short* Wo_bf = Wr_bf + (size_t)H * H;
  unsigned short* x_bf  = Wo_bf + (size_t)DOUT * H;

  hipMemsetAsync(w, 0, 1 << 14, stream);  // zero S, v

  dim3 t256(256);
  spec_col3<<<dim3(4, 16, 3), t256, 0, stream>>>(W_in, W_rec, W_out, u_in, u_rec, u_out, v);
  norm3<<<3, t256, 0, stream>>>(v, S);
  rowsq3<<<2304, t256, 0, stream>>>(W_in, W_rec, W_out, v, S);
  spec_finalize<<<1, 64, 0, stream>>>(S);
  cvt_pack_all<<<1024, t256, 0, stream>>>((const float4*)W_in, (const float4*)W_rec,
                                          (const float4*)W_out, (const float4*)x, S,
                                          Wi_bf, Wr_bf, Wo_bf, (ushort4*)x_bf);

  Mods mods;
  for (int t = 0; t < 32; ++t) mods.m[t] = (float)(1.0 + 0.1 * sin(0.3 * (double)t));

  rnn_stream<<<256, 512, 0, stream>>>(x_bf, Wi_bf, Wr_bf, Wo_bf,
                                      b_in, b_rec, b_out, (float*)d_out, mods);
}